// Round 1
// baseline (539.708 us; speedup 1.0000x reference)
//
#include <hip/hip_runtime.h>
#include <hip/hip_bf16.h>

// Switch-Transformer FFN, top-1 routing. B=4,S=4096,D=1024,F=2048,E=8.
// Pipeline: router(fp32)+bucketize+x->bf16 | W1/W2 transpose->bf16 |
// grouped GEMM1 (GELU epi, h bf16) | grouped GEMM2 (scale epi, fp32 out).

typedef __attribute__((ext_vector_type(8))) short short8;
typedef __attribute__((ext_vector_type(4))) float f32x4;

struct __align__(8) us4 { unsigned short x, y, z, w; };

__device__ __forceinline__ void gload16(const void* g, void* l) {
  __builtin_amdgcn_global_load_lds(
      (const __attribute__((address_space(1))) unsigned int*)g,
      (__attribute__((address_space(3))) unsigned int*)l, 16, 0, 0);
}

__device__ __forceinline__ unsigned short f2b(float f) {
  union { float f; unsigned u; } v; v.f = f;
  unsigned r = v.u + 0x7FFFu + ((v.u >> 16) & 1u);   // RNE
  return (unsigned short)(r >> 16);
}

// ---------------- router: logits, softmax top-1, bucket scatter, x->bf16 ----
__global__ __launch_bounds__(256) void router_kernel(
    const float* __restrict__ x, const float* __restrict__ Wr,
    const float* __restrict__ br, float* __restrict__ wts,
    int* __restrict__ cnt, int* __restrict__ list,
    unsigned short* __restrict__ xb)
{
  const int lane = threadIdx.x & 63;
  const int wid  = threadIdx.x >> 6;
  const int t = blockIdx.x * 4 + wid;          // token id, one wave per token

  const float4* x4 = (const float4*)(x + (size_t)t * 1024);
  float acc[8];
#pragma unroll
  for (int e = 0; e < 8; ++e) acc[e] = 0.f;
  float4 xv[4];
#pragma unroll
  for (int i = 0; i < 4; ++i) {
    float4 v = x4[lane + 64 * i];
    xv[i] = v;
    const int d = (lane + 64 * i) * 4;
    const float* wr = Wr + (size_t)d * 8;
    float xs[4] = {v.x, v.y, v.z, v.w};
#pragma unroll
    for (int j = 0; j < 4; ++j) {
      float4 w0 = *(const float4*)(wr + j * 8);
      float4 w1 = *(const float4*)(wr + j * 8 + 4);
      acc[0] += xs[j] * w0.x; acc[1] += xs[j] * w0.y;
      acc[2] += xs[j] * w0.z; acc[3] += xs[j] * w0.w;
      acc[4] += xs[j] * w1.x; acc[5] += xs[j] * w1.y;
      acc[6] += xs[j] * w1.z; acc[7] += xs[j] * w1.w;
    }
  }
  // bf16 copy of x (feeds GEMM1 A staging)
#pragma unroll
  for (int i = 0; i < 4; ++i) {
    us4 o;
    o.x = f2b(xv[i].x); o.y = f2b(xv[i].y); o.z = f2b(xv[i].z); o.w = f2b(xv[i].w);
    *(us4*)(xb + (size_t)t * 1024 + (size_t)(lane + 64 * i) * 4) = o;
  }
  // wave-wide butterfly reduce for the 8 logits
#pragma unroll
  for (int e = 0; e < 8; ++e) {
    float v = acc[e];
#pragma unroll
    for (int m = 32; m; m >>= 1) v += __shfl_xor(v, m, 64);
    acc[e] = v;
  }
  if (lane == 0) {
    float lg[8];
#pragma unroll
    for (int e = 0; e < 8; ++e) lg[e] = acc[e] + br[e];
    float mx = lg[0]; int bi = 0;
#pragma unroll
    for (int e = 1; e < 8; ++e) if (lg[e] > mx) { mx = lg[e]; bi = e; }  // first-max, matches argmax
    float s = 0.f;
#pragma unroll
    for (int e = 0; e < 8; ++e) s += expf(lg[e] - mx);
    wts[t] = 1.0f / s;                          // max softmax prob = exp(0)/s
    int pos = atomicAdd(&cnt[bi], 1);
    list[bi * 16384 + pos] = t;
  }
}

// ---------------- W[k][n] fp32 -> Wt[n][k] bf16 (per expert) ----------------
__global__ __launch_bounds__(256) void transpose_cvt(
    const float* __restrict__ W, unsigned short* __restrict__ Wt, int K, int N)
{
  __shared__ float tl[64][65];
  const int e = blockIdx.z;
  const float* Wp = W + (size_t)e * K * N;
  unsigned short* Wtp = Wt + (size_t)e * K * N;
  const int k0 = blockIdx.y * 64, n0 = blockIdx.x * 64;
  const int r = threadIdx.x >> 4, c4 = (threadIdx.x & 15) * 4;
#pragma unroll
  for (int i = 0; i < 4; ++i) {
    float4 v = *(const float4*)(Wp + (size_t)(k0 + r + i * 16) * N + n0 + c4);
    tl[r + i * 16][c4 + 0] = v.x; tl[r + i * 16][c4 + 1] = v.y;
    tl[r + i * 16][c4 + 2] = v.z; tl[r + i * 16][c4 + 3] = v.w;
  }
  __syncthreads();
#pragma unroll
  for (int i = 0; i < 4; ++i) {
    const int n = r + i * 16;
    us4 o;
    o.x = f2b(tl[c4 + 0][n]); o.y = f2b(tl[c4 + 1][n]);
    o.z = f2b(tl[c4 + 2][n]); o.w = f2b(tl[c4 + 3][n]);
    *(us4*)(Wtp + (size_t)(n0 + n) * K + k0 + c4) = o;
  }
}

// ---------------- grouped GEMM: gathered-A rows x Bt[e], m97 structure ------
// EPI==1: h[tok][col] = bf16(gelu(acc + b1))      (N=F)
// EPI==2: out[tok][col] = (acc + b2) * wt[tok]    (N=D, fp32)
template <int K, int N, int EPI>
__global__ __launch_bounds__(256) void gemm_moe(
    const unsigned short* __restrict__ A,    // [*, K] bf16, rows gathered by token
    const unsigned short* __restrict__ Bt,   // [8][N][K] bf16
    const float* __restrict__ bias,          // [8][N]
    const int* __restrict__ cnt, const int* __restrict__ list,
    const float* __restrict__ wts, void* __restrict__ outp)
{
  constexpr int BM = 128, BN = 128, BK = 32, NKT = K / BK;
  __shared__ __align__(16) unsigned short sm[2][2][BM][BK];  // [buf][A/B][row][k], chunk-swizzled
  __shared__ int tok_s[BM];
  __shared__ float wt_s[BM];

  const int tid = threadIdx.x;
  const int lane = tid & 63, wid = tid >> 6;
  const int e = blockIdx.z;
  const int cnt_e = cnt[e];
  const int row0 = blockIdx.y * BM;
  if (row0 >= cnt_e) return;
  const int n0 = blockIdx.x * BN;

  if (tid < BM) {
    const int s = row0 + tid;
    const int tok = (s < cnt_e) ? list[e * 16384 + s] : 0;
    tok_s[tid] = tok;
    wt_s[tid] = (EPI == 2) ? wts[tok] : 0.f;
  }
  __syncthreads();

  // --- staging addresses (global_load_lds: linear LDS dest, swizzled source)
  // lane covers row r = inst_row0 + (lane>>2), chunk-slot (lane&3).
  // LDS slot c of row r holds global chunk c ^ swz(r), swz(r)=(r&3)^((r>>2)&3).
  const int swzW = ((lane >> 2) & 3) ^ ((lane >> 4) & 3);
  const int gch  = (((lane & 3) ^ swzW)) * 8;   // element offset of source chunk
  const int rS0 = (wid * 2 + 0) * 16 + (lane >> 2);
  const int rS1 = (wid * 2 + 1) * 16 + (lane >> 2);
  const unsigned short* aS0 = A + (size_t)tok_s[rS0] * K + gch;
  const unsigned short* aS1 = A + (size_t)tok_s[rS1] * K + gch;
  const unsigned short* bS0 = Bt + ((size_t)e * N + n0 + rS0) * K + gch;
  const unsigned short* bS1 = Bt + ((size_t)e * N + n0 + rS1) * K + gch;

  // --- fragment read offsets (swz folds to a per-lane constant)
  const int mrow = (wid >> 1) * 64 + (lane & 15);
  const int nrow = (wid & 1) * 64 + (lane & 15);
  const int fch  = (((lane >> 4) ^ (lane & 3) ^ ((lane >> 2) & 3))) * 8;

  f32x4 acc[4][4];
#pragma unroll
  for (int i = 0; i < 4; ++i)
#pragma unroll
    for (int j = 0; j < 4; ++j) acc[i][j] = (f32x4){0.f, 0.f, 0.f, 0.f};

  auto stage = [&](int buf, int kt) {
    const size_t ko = (size_t)kt * BK;
    gload16(aS0 + ko, &sm[buf][0][(wid * 2 + 0) * 16][0]);
    gload16(aS1 + ko, &sm[buf][0][(wid * 2 + 1) * 16][0]);
    gload16(bS0 + ko, &sm[buf][1][(wid * 2 + 0) * 16][0]);
    gload16(bS1 + ko, &sm[buf][1][(wid * 2 + 1) * 16][0]);
  };
  auto compute = [&](int buf) {
    short8 af[4], bfr[4];
#pragma unroll
    for (int mf = 0; mf < 4; ++mf)
      af[mf] = *(const short8*)&sm[buf][0][mrow + mf * 16][fch];
#pragma unroll
    for (int nf = 0; nf < 4; ++nf)
      bfr[nf] = *(const short8*)&sm[buf][1][nrow + nf * 16][fch];
#pragma unroll
    for (int mf = 0; mf < 4; ++mf)
#pragma unroll
      for (int nf = 0; nf < 4; ++nf)
        acc[mf][nf] = __builtin_amdgcn_mfma_f32_16x16x32_bf16(
            af[mf], bfr[nf], acc[mf][nf], 0, 0, 0);
  };

  stage(0, 0);
  __syncthreads();
#pragma unroll 1
  for (int kt = 0; kt < NKT; kt += 2) {
    stage(1, kt + 1);          // kt+1 <= NKT-1 always (NKT even)
    compute(0);
    __syncthreads();
    if (kt + 2 < NKT) stage(0, kt + 2);
    compute(1);
    __syncthreads();
  }

  // --- epilogue; C mapping: col = lane&15, row = (lane>>4)*4 + reg
  const int cRow0 = (wid >> 1) * 64 + (lane >> 4) * 4;
  const int cColB = n0 + (wid & 1) * 64 + (lane & 15);
  if (EPI == 1) {
    unsigned short* H = (unsigned short*)outp;
#pragma unroll
    for (int nf = 0; nf < 4; ++nf) {
      const int col = cColB + nf * 16;
      const float bv = bias[e * N + col];
#pragma unroll
      for (int mf = 0; mf < 4; ++mf)
#pragma unroll
        for (int r = 0; r < 4; ++r) {
          const int sl = cRow0 + mf * 16 + r;
          if (row0 + sl < cnt_e) {
            float v = acc[mf][nf][r] + bv;
            v = 0.5f * v * (1.0f + erff(v * 0.70710678118654752f));  // exact GELU
            H[(size_t)tok_s[sl] * N + col] = f2b(v);
          }
        }
    }
  } else {
    float* O = (float*)outp;
#pragma unroll
    for (int nf = 0; nf < 4; ++nf) {
      const int col = cColB + nf * 16;
      const float bv = bias[e * N + col];
#pragma unroll
      for (int mf = 0; mf < 4; ++mf)
#pragma unroll
        for (int r = 0; r < 4; ++r) {
          const int sl = cRow0 + mf * 16 + r;
          if (row0 + sl < cnt_e) {
            O[(size_t)tok_s[sl] * N + col] = (acc[mf][nf][r] + bv) * wt_s[sl];
          }
        }
    }
  }
}

// ---------------------------------------------------------------------------
extern "C" void kernel_launch(void* const* d_in, const int* in_sizes, int n_in,
                              void* d_out, int out_size, void* d_ws, size_t ws_size,
                              hipStream_t stream) {
  const float* x  = (const float*)d_in[0];   // [4,4096,1024]
  const float* Wr = (const float*)d_in[1];   // [1024,8]
  const float* br = (const float*)d_in[2];   // [8]
  const float* W1 = (const float*)d_in[3];   // [8,1024,2048]
  const float* b1 = (const float*)d_in[4];   // [8,2048]
  const float* W2 = (const float*)d_in[5];   // [8,2048,1024]
  const float* b2 = (const float*)d_in[6];   // [8,1024]

  // workspace layout (~161 MB)
  char* ws = (char*)d_ws;
  int*   cnt  = (int*)ws;                               // 8 ints
  float* wts  = (float*)(ws + 256);                     // 16384 f32
  int*   list = (int*)(ws + 256 + 64 * 1024);           // 8*16384 int
  unsigned short* xb  = (unsigned short*)(ws + 1024 * 1024);     // 32 MB
  unsigned short* w1t = xb  + (size_t)16384 * 1024;              // 32 MB [8][2048][1024]
  unsigned short* w2t = w1t + (size_t)8 * 2048 * 1024;           // 32 MB [8][1024][2048]
  unsigned short* h   = w2t + (size_t)8 * 1024 * 2048;           // 64 MB [16384][2048]

  hipMemsetAsync(cnt, 0, 32, stream);
  router_kernel<<<dim3(4096), 256, 0, stream>>>(x, Wr, br, wts, cnt, list, xb);
  transpose_cvt<<<dim3(32, 16, 8), 256, 0, stream>>>(W1, w1t, 1024, 2048);
  transpose_cvt<<<dim3(16, 32, 8), 256, 0, stream>>>(W2, w2t, 2048, 1024);
  gemm_moe<1024, 2048, 1><<<dim3(16, 128, 8), 256, 0, stream>>>(
      xb, w1t, b1, cnt, list, wts, (void*)h);
  gemm_moe<2048, 1024, 2><<<dim3(8, 128, 8), 256, 0, stream>>>(
      h, w2t, b2, cnt, list, wts, d_out);
}

// Round 2
// 415.245 us; speedup vs baseline: 1.2997x; 1.2997x over previous
//
#include <hip/hip_runtime.h>
#include <hip/hip_bf16.h>

// Switch-Transformer FFN, top-1 routing. B=4,S=4096,D=1024,F=2048,E=8.
// Pipeline: router_logits(fp32, no atomics) | bucketize (LDS-batched atomics) |
// W1/W2 transpose->bf16 | grouped GEMM1 (GELU epi, h bf16) |
// grouped GEMM2 (scale epi, fp32 out).

typedef __attribute__((ext_vector_type(8))) short short8;
typedef __attribute__((ext_vector_type(4))) float f32x4;

struct __align__(8) us4 { unsigned short x, y, z, w; };

__device__ __forceinline__ void gload16(const void* g, void* l) {
  __builtin_amdgcn_global_load_lds(
      (const __attribute__((address_space(1))) unsigned int*)g,
      (__attribute__((address_space(3))) unsigned int*)l, 16, 0, 0);
}

__device__ __forceinline__ unsigned short f2b(float f) {
  union { float f; unsigned u; } v; v.f = f;
  unsigned r = v.u + 0x7FFFu + ((v.u >> 16) & 1u);   // RNE
  return (unsigned short)(r >> 16);
}

// ---------------- router: logits, softmax top-1 weight + expert id, x->bf16 -
__global__ __launch_bounds__(256) void router_logits(
    const float* __restrict__ x, const float* __restrict__ Wr,
    const float* __restrict__ br, float* __restrict__ wts,
    int* __restrict__ eidx, unsigned short* __restrict__ xb)
{
  const int lane = threadIdx.x & 63;
  const int wid  = threadIdx.x >> 6;
  const int t = blockIdx.x * 4 + wid;          // token id, one wave per token

  const float4* x4 = (const float4*)(x + (size_t)t * 1024);
  float acc[8];
#pragma unroll
  for (int e = 0; e < 8; ++e) acc[e] = 0.f;
  float4 xv[4];
#pragma unroll
  for (int i = 0; i < 4; ++i) {
    float4 v = x4[lane + 64 * i];
    xv[i] = v;
    const int d = (lane + 64 * i) * 4;
    const float* wr = Wr + (size_t)d * 8;
    float xs[4] = {v.x, v.y, v.z, v.w};
#pragma unroll
    for (int j = 0; j < 4; ++j) {
      float4 w0 = *(const float4*)(wr + j * 8);
      float4 w1 = *(const float4*)(wr + j * 8 + 4);
      acc[0] += xs[j] * w0.x; acc[1] += xs[j] * w0.y;
      acc[2] += xs[j] * w0.z; acc[3] += xs[j] * w0.w;
      acc[4] += xs[j] * w1.x; acc[5] += xs[j] * w1.y;
      acc[6] += xs[j] * w1.z; acc[7] += xs[j] * w1.w;
    }
  }
  // bf16 copy of x (feeds GEMM1 A staging)
#pragma unroll
  for (int i = 0; i < 4; ++i) {
    us4 o;
    o.x = f2b(xv[i].x); o.y = f2b(xv[i].y); o.z = f2b(xv[i].z); o.w = f2b(xv[i].w);
    *(us4*)(xb + (size_t)t * 1024 + (size_t)(lane + 64 * i) * 4) = o;
  }
  // wave-wide butterfly reduce for the 8 logits
#pragma unroll
  for (int e = 0; e < 8; ++e) {
    float v = acc[e];
#pragma unroll
    for (int m = 32; m; m >>= 1) v += __shfl_xor(v, m, 64);
    acc[e] = v;
  }
  if (lane == 0) {
    float lg[8];
#pragma unroll
    for (int e = 0; e < 8; ++e) lg[e] = acc[e] + br[e];
    float mx = lg[0]; int bi = 0;
#pragma unroll
    for (int e = 1; e < 8; ++e) if (lg[e] > mx) { mx = lg[e]; bi = e; }  // first-max == argmax
    float s = 0.f;
#pragma unroll
    for (int e = 0; e < 8; ++e) s += expf(lg[e] - mx);
    wts[t]  = 1.0f / s;                         // max softmax prob = exp(0)/s
    eidx[t] = bi;
  }
}

// ---------------- bucketize: LDS histogram + 8 global atomics per block -----
__global__ __launch_bounds__(256) void bucketize(
    const int* __restrict__ eidx, int* __restrict__ cnt, int* __restrict__ list)
{
  __shared__ int lcnt[8], base[8];
  const int tid = threadIdx.x;
  if (tid < 8) lcnt[tid] = 0;
  __syncthreads();
  const int t = blockIdx.x * 256 + tid;
  const int e = eidx[t];
  const int lpos = atomicAdd(&lcnt[e], 1);      // LDS atomic: cheap
  __syncthreads();
  if (tid < 8) base[tid] = atomicAdd(&cnt[tid], lcnt[tid]);  // 8 per block
  __syncthreads();
  list[e * 16384 + base[e] + lpos] = t;         // list order is irrelevant
}

// ---------------- W[k][n] fp32 -> Wt[n][k] bf16 (per expert) ----------------
__global__ __launch_bounds__(256) void transpose_cvt(
    const float* __restrict__ W, unsigned short* __restrict__ Wt, int K, int N)
{
  __shared__ float tl[64][65];
  const int e = blockIdx.z;
  const float* Wp = W + (size_t)e * K * N;
  unsigned short* Wtp = Wt + (size_t)e * K * N;
  const int k0 = blockIdx.y * 64, n0 = blockIdx.x * 64;
  const int r = threadIdx.x >> 4, c4 = (threadIdx.x & 15) * 4;
#pragma unroll
  for (int i = 0; i < 4; ++i) {
    float4 v = *(const float4*)(Wp + (size_t)(k0 + r + i * 16) * N + n0 + c4);
    tl[r + i * 16][c4 + 0] = v.x; tl[r + i * 16][c4 + 1] = v.y;
    tl[r + i * 16][c4 + 2] = v.z; tl[r + i * 16][c4 + 3] = v.w;
  }
  __syncthreads();
#pragma unroll
  for (int i = 0; i < 4; ++i) {
    const int n = r + i * 16;
    us4 o;
    o.x = f2b(tl[c4 + 0][n]); o.y = f2b(tl[c4 + 1][n]);
    o.z = f2b(tl[c4 + 2][n]); o.w = f2b(tl[c4 + 3][n]);
    *(us4*)(Wtp + (size_t)(n0 + n) * K + k0 + c4) = o;
  }
}

// ---------------- grouped GEMM: gathered-A rows x Bt[e], m97 structure ------
// EPI==1: h[tok][col] = bf16(gelu(acc + b1))      (N=F)
// EPI==2: out[tok][col] = (acc + b2) * wt[tok]    (N=D, fp32)
template <int K, int N, int EPI>
__global__ __launch_bounds__(256) void gemm_moe(
    const unsigned short* __restrict__ A,    // [*, K] bf16, rows gathered by token
    const unsigned short* __restrict__ Bt,   // [8][N][K] bf16
    const float* __restrict__ bias,          // [8][N]
    const int* __restrict__ cnt, const int* __restrict__ list,
    const float* __restrict__ wts, void* __restrict__ outp)
{
  constexpr int BM = 128, BN = 128, BK = 32, NKT = K / BK;
  __shared__ __align__(16) unsigned short sm[2][2][BM][BK];  // [buf][A/B][row][k], chunk-swizzled
  __shared__ int tok_s[BM];
  __shared__ float wt_s[BM];

  const int tid = threadIdx.x;
  const int lane = tid & 63, wid = tid >> 6;
  const int e = blockIdx.z;
  const int cnt_e = cnt[e];
  const int row0 = blockIdx.y * BM;
  if (row0 >= cnt_e) return;
  const int n0 = blockIdx.x * BN;

  if (tid < BM) {
    const int s = row0 + tid;
    const int tok = (s < cnt_e) ? list[e * 16384 + s] : 0;
    tok_s[tid] = tok;
    wt_s[tid] = (EPI == 2) ? wts[tok] : 0.f;
  }
  __syncthreads();

  // --- staging addresses (global_load_lds: linear LDS dest, swizzled source)
  const int swzW = ((lane >> 2) & 3) ^ ((lane >> 4) & 3);
  const int gch  = (((lane & 3) ^ swzW)) * 8;   // element offset of source chunk
  const int rS0 = (wid * 2 + 0) * 16 + (lane >> 2);
  const int rS1 = (wid * 2 + 1) * 16 + (lane >> 2);
  const unsigned short* aS0 = A + (size_t)tok_s[rS0] * K + gch;
  const unsigned short* aS1 = A + (size_t)tok_s[rS1] * K + gch;
  const unsigned short* bS0 = Bt + ((size_t)e * N + n0 + rS0) * K + gch;
  const unsigned short* bS1 = Bt + ((size_t)e * N + n0 + rS1) * K + gch;

  // --- fragment read offsets (swz folds to a per-lane constant)
  const int mrow = (wid >> 1) * 64 + (lane & 15);
  const int nrow = (wid & 1) * 64 + (lane & 15);
  const int fch  = (((lane >> 4) ^ (lane & 3) ^ ((lane >> 2) & 3))) * 8;

  f32x4 acc[4][4];
#pragma unroll
  for (int i = 0; i < 4; ++i)
#pragma unroll
    for (int j = 0; j < 4; ++j) acc[i][j] = (f32x4){0.f, 0.f, 0.f, 0.f};

  auto stage = [&](int buf, int kt) {
    const size_t ko = (size_t)kt * BK;
    gload16(aS0 + ko, &sm[buf][0][(wid * 2 + 0) * 16][0]);
    gload16(aS1 + ko, &sm[buf][0][(wid * 2 + 1) * 16][0]);
    gload16(bS0 + ko, &sm[buf][1][(wid * 2 + 0) * 16][0]);
    gload16(bS1 + ko, &sm[buf][1][(wid * 2 + 1) * 16][0]);
  };
  auto compute = [&](int buf) {
    short8 af[4], bfr[4];
#pragma unroll
    for (int mf = 0; mf < 4; ++mf)
      af[mf] = *(const short8*)&sm[buf][0][mrow + mf * 16][fch];
#pragma unroll
    for (int nf = 0; nf < 4; ++nf)
      bfr[nf] = *(const short8*)&sm[buf][1][nrow + nf * 16][fch];
#pragma unroll
    for (int mf = 0; mf < 4; ++mf)
#pragma unroll
      for (int nf = 0; nf < 4; ++nf)
        acc[mf][nf] = __builtin_amdgcn_mfma_f32_16x16x32_bf16(
            af[mf], bfr[nf], acc[mf][nf], 0, 0, 0);
  };

  stage(0, 0);
  __syncthreads();
#pragma unroll 1
  for (int kt = 0; kt < NKT; kt += 2) {
    stage(1, kt + 1);
    compute(0);
    __syncthreads();
    if (kt + 2 < NKT) stage(0, kt + 2);
    compute(1);
    __syncthreads();
  }

  // --- epilogue; C mapping: col = lane&15, row = (lane>>4)*4 + reg
  const int cRow0 = (wid >> 1) * 64 + (lane >> 4) * 4;
  const int cColB = n0 + (wid & 1) * 64 + (lane & 15);
  if (EPI == 1) {
    unsigned short* H = (unsigned short*)outp;
#pragma unroll
    for (int nf = 0; nf < 4; ++nf) {
      const int col = cColB + nf * 16;
      const float bv = bias[e * N + col];
#pragma unroll
      for (int mf = 0; mf < 4; ++mf)
#pragma unroll
        for (int r = 0; r < 4; ++r) {
          const int sl = cRow0 + mf * 16 + r;
          if (row0 + sl < cnt_e) {
            float v = acc[mf][nf][r] + bv;
            v = 0.5f * v * (1.0f + erff(v * 0.70710678118654752f));  // exact GELU
            H[(size_t)tok_s[sl] * N + col] = f2b(v);
          }
        }
    }
  } else {
    float* O = (float*)outp;
#pragma unroll
    for (int nf = 0; nf < 4; ++nf) {
      const int col = cColB + nf * 16;
      const float bv = bias[e * N + col];
#pragma unroll
      for (int mf = 0; mf < 4; ++mf)
#pragma unroll
        for (int r = 0; r < 4; ++r) {
          const int sl = cRow0 + mf * 16 + r;
          if (row0 + sl < cnt_e) {
            O[(size_t)tok_s[sl] * N + col] = (acc[mf][nf][r] + bv) * wt_s[sl];
          }
        }
    }
  }
}

// ---------------------------------------------------------------------------
extern "C" void kernel_launch(void* const* d_in, const int* in_sizes, int n_in,
                              void* d_out, int out_size, void* d_ws, size_t ws_size,
                              hipStream_t stream) {
  const float* x  = (const float*)d_in[0];   // [4,4096,1024]
  const float* Wr = (const float*)d_in[1];   // [1024,8]
  const float* br = (const float*)d_in[2];   // [8]
  const float* W1 = (const float*)d_in[3];   // [8,1024,2048]
  const float* b1 = (const float*)d_in[4];   // [8,2048]
  const float* W2 = (const float*)d_in[5];   // [8,2048,1024]
  const float* b2 = (const float*)d_in[6];   // [8,1024]

  // workspace layout (~161 MB)
  char* ws = (char*)d_ws;
  int*   cnt  = (int*)ws;                                  // 8 ints
  float* wts  = (float*)(ws + 256);                        // 16384 f32
  int*   eidx = (int*)(ws + 256 + 64 * 1024);              // 16384 int
  int*   list = (int*)(ws + 256 + 128 * 1024);             // 8*16384 int
  unsigned short* xb  = (unsigned short*)(ws + 1024 * 1024);     // 32 MB
  unsigned short* w1t = xb  + (size_t)16384 * 1024;              // 32 MB [8][2048][1024]
  unsigned short* w2t = w1t + (size_t)8 * 2048 * 1024;           // 32 MB [8][1024][2048]
  unsigned short* h   = w2t + (size_t)8 * 1024 * 2048;           // 64 MB [16384][2048]

  hipMemsetAsync(cnt, 0, 32, stream);
  router_logits<<<dim3(4096), 256, 0, stream>>>(x, Wr, br, wts, eidx, xb);
  bucketize<<<dim3(64), 256, 0, stream>>>(eidx, cnt, list);
  transpose_cvt<<<dim3(32, 16, 8), 256, 0, stream>>>(W1, w1t, 1024, 2048);
  transpose_cvt<<<dim3(16, 32, 8), 256, 0, stream>>>(W2, w2t, 2048, 1024);
  gemm_moe<1024, 2048, 1><<<dim3(16, 128, 8), 256, 0, stream>>>(
      xb, w1t, b1, cnt, list, wts, (void*)h);
  gemm_moe<2048, 1024, 2><<<dim3(8, 128, 8), 256, 0, stream>>>(
      h, w2t, b2, cnt, list, wts, d_out);
}